// Round 8
// baseline (39.846 us; speedup 1.0000x reference)
//
#include <hip/hip_runtime.h>

// E = 8*128*128 edges; MLP 16->128->256->128->(32x32 folded to 32)
// fp16 MFMA 16x16x32, swapped operands (W as A-frag -> lane owns one edge).
// Round 8 = round 7 resubmit (container died): LDS 50->33 KB (4 blocks/CU):
// L1 A-frags built directly from global (staging phase deleted), L2/L3 split
// into two col-halves through a single 64x132 X2-half buffer with L3
// partials held in registers.

typedef _Float16 f16;
typedef _Float16 f16x8 __attribute__((ext_vector_type(8)));
typedef __fp16 fp16x2 __attribute__((ext_vector_type(2)));   // cvt_pkrtz return type
typedef float f32x4 __attribute__((ext_vector_type(4)));

#define OFF_W1S 0        // [8 ct][64 lane][8]   (K=16 padded: row16 = b1)
#define OFF_W2S 4096     // [16 ct][4 kt][64][8]
#define OFF_W3S 36864    // [8 ct][8 kt][64][8]
#define OFF_W4S 69632    // [2 ct][4 kt][64][8]  (W4 folded over inner i)
#define WS_HALFS 73728

union U16x8 { struct { uint2 lo, hi; } p; f16x8 v; };
union U32x2 { fp16x2 h2[2]; uint2 u; };

// ---------------------------------------------------------------------------
// Pre-kernel: fold W4 over i, convert weights to fp16 in fragment order:
// element j of lane l for col-tile ct, k-tile kt is
// W[kt*32 + (l>>4)*8 + j][ct*16 + (l&15)].  W1 row 16 carries b1.
// ---------------------------------------------------------------------------
__global__ void prep_kernel(const float* __restrict__ W1, const float* __restrict__ b1,
                            const float* __restrict__ W2, const float* __restrict__ W3,
                            const float* __restrict__ W4, const float* __restrict__ b4,
                            f16* __restrict__ wsh, float* __restrict__ b4r) {
  int t = blockIdx.x * 256 + threadIdx.x;
  if (t < 4096) {                       // W1s (K 16 + bias row + zeros)
    int j = t & 7, l = (t >> 3) & 63, ct = t >> 9;
    int k = ((l >> 4) & 3) * 8 + j, c = ct * 16 + (l & 15);
    wsh[OFF_W1S + t] = (k < 16) ? (f16)W1[k * 128 + c]
                                : (k == 16 ? (f16)b1[c] : (f16)0.f);
  } else if (t < 36864) {               // W2s
    int s = t - 4096;
    int j = s & 7, l = (s >> 3) & 63, kt = (s >> 9) & 3, ct = s >> 11;
    int k = kt * 32 + ((l >> 4) & 3) * 8 + j, c = ct * 16 + (l & 15);
    wsh[t] = (f16)W2[k * 256 + c];
  } else if (t < 69632) {               // W3s
    int s = t - 36864;
    int j = s & 7, l = (s >> 3) & 63, kt = (s >> 9) & 7, ct = s >> 12;
    int k = kt * 32 + ((l >> 4) & 3) * 8 + j, c = ct * 16 + (l & 15);
    wsh[t] = (f16)W3[k * 128 + c];
  } else if (t < 73728) {               // W4rs (folded over i)
    int s = t - 69632;
    int j = s & 7, l = (s >> 3) & 63, kt = (s >> 9) & 3, ct = s >> 11;
    int k = kt * 32 + ((l >> 4) & 3) * 8 + j, o = ct * 16 + (l & 15);
    float a = 0.f;
#pragma unroll
    for (int i = 0; i < 32; ++i) a += W4[k * 1024 + o * 32 + i];
    wsh[t] = (f16)a;
  }
  if (t < 32) {
    float a = 0.f;
#pragma unroll
    for (int i = 0; i < 32; ++i) a += b4[t * 32 + i];
    b4r[t] = a;
  }
}

// ---------------------------------------------------------------------------
// Fused MLP, 64 edges/block, 4 waves, col-sliced, 6 phases / 5 barriers:
//   L1 | L2a (X2 cols 0..127) | L3a (partial acc) | L2b (cols 128..255)
//      | L3b (finish, write X3) | L4
// LDS: B1 = X1 then X3 (16.5 KB); B2 = X2 half (16.5 KB).  33 KB total.
// ---------------------------------------------------------------------------
__global__ __launch_bounds__(256, 4) void mlp_mfma_kernel(
    const float* __restrict__ e_vw, const float* __restrict__ h_w,
    const float* __restrict__ b2, const float* __restrict__ b3,
    const f16* __restrict__ wsh, const float* __restrict__ b4r,
    float* __restrict__ out) {
  __shared__ f16 B1[64 * 132];
  __shared__ f16 B2[64 * 132];

  const int l  = threadIdx.x & 63;
  const int w  = threadIdx.x >> 6;
  const int e0 = l & 15;          // edge-within-tile
  const int kg = l >> 4;          // k-group; packed cols kg*4..kg*4+3
  const size_t row0 = (size_t)blockIdx.x * 64;

  const f16x8* wp1 = (const f16x8*)(wsh + OFF_W1S);
  const f16x8* wp2 = (const f16x8*)(wsh + OFF_W2S);
  const f16x8* wp3 = (const f16x8*)(wsh + OFF_W3S);
  const f16x8* wp4 = (const f16x8*)(wsh + OFF_W4S);

  // ---- Phase 0: L1 (A-frag direct from global; bias folded in K-pad) ----
  f16x8 bfr1[2];
#pragma unroll
  for (int c = 0; c < 2; ++c) bfr1[c] = wp1[(2 * w + c) * 64 + l];

#pragma unroll
  for (int t = 0; t < 4; ++t) {
    U16x8 a;
    if (kg < 2) {
      const float* pe = e_vw + (row0 + t * 16 + e0) * 16 + kg * 8;
      float4 v0 = *reinterpret_cast<const float4*>(pe);
      float4 v1 = *reinterpret_cast<const float4*>(pe + 4);
      U32x2 c0, c1;
      c0.h2[0] = __builtin_amdgcn_cvt_pkrtz(v0.x, v0.y);
      c0.h2[1] = __builtin_amdgcn_cvt_pkrtz(v0.z, v0.w);
      c1.h2[0] = __builtin_amdgcn_cvt_pkrtz(v1.x, v1.y);
      c1.h2[1] = __builtin_amdgcn_cvt_pkrtz(v1.z, v1.w);
      a.p.lo = c0.u; a.p.hi = c1.u;
    } else {
      a.p.lo.x = (kg == 2) ? 0x00003C00u : 0u;   // k=16 -> 1.0 (bias slot)
      a.p.lo.y = 0u; a.p.hi.x = 0u; a.p.hi.y = 0u;
    }
#pragma unroll
    for (int c = 0; c < 2; ++c) {
      f32x4 acc = {0.f, 0.f, 0.f, 0.f};
      acc = __builtin_amdgcn_mfma_f32_16x16x32_f16(bfr1[c], a.v, acc, 0, 0, 0);
      U32x2 o;
      o.h2[0] = __builtin_amdgcn_cvt_pkrtz(fmaxf(acc[0], 0.f), fmaxf(acc[1], 0.f));
      o.h2[1] = __builtin_amdgcn_cvt_pkrtz(fmaxf(acc[2], 0.f), fmaxf(acc[3], 0.f));
      *reinterpret_cast<uint2*>(B1 + (t * 16 + e0) * 132 + (2 * w + c) * 16 + kg * 4) = o.u;
    }
  }
  // prefetch L2a frags (latency overlaps the barrier)
  f16x8 bfa[8];
#pragma unroll
  for (int c = 0; c < 2; ++c)
#pragma unroll
    for (int kt = 0; kt < 4; ++kt)
      bfa[c * 4 + kt] = wp2[((2 * w + c) * 4 + kt) * 64 + l];
  __syncthreads();

  // ---- Phase 1: L2a -> X2 cols [0,128) into B2 ----
  f16x8 bfb[8];   // prefetch L3a frags during L2a
#pragma unroll
  for (int c = 0; c < 2; ++c)
#pragma unroll
    for (int kt = 0; kt < 4; ++kt)
      bfb[c * 4 + kt] = wp3[((2 * w + c) * 8 + kt) * 64 + l];
  {
    float4 bb[2];
#pragma unroll
    for (int c = 0; c < 2; ++c)
      bb[c] = *reinterpret_cast<const float4*>(b2 + (2 * w + c) * 16 + kg * 4);
#pragma unroll
    for (int t = 0; t < 4; ++t) {
      const f16* pa = B1 + (t * 16 + e0) * 132 + kg * 8;
      U16x8 a[4];
#pragma unroll
      for (int kt = 0; kt < 4; ++kt) {
        a[kt].p.lo = *(const uint2*)(pa + kt * 32);
        a[kt].p.hi = *(const uint2*)(pa + kt * 32 + 4);
      }
#pragma unroll
      for (int c = 0; c < 2; ++c) {
        f32x4 acc = {0.f, 0.f, 0.f, 0.f};
#pragma unroll
        for (int kt = 0; kt < 4; ++kt)
          acc = __builtin_amdgcn_mfma_f32_16x16x32_f16(bfa[c * 4 + kt], a[kt].v, acc, 0, 0, 0);
        U32x2 o;
        o.h2[0] = __builtin_amdgcn_cvt_pkrtz(fmaxf(acc[0] + bb[c].x, 0.f),
                                             fmaxf(acc[1] + bb[c].y, 0.f));
        o.h2[1] = __builtin_amdgcn_cvt_pkrtz(fmaxf(acc[2] + bb[c].z, 0.f),
                                             fmaxf(acc[3] + bb[c].w, 0.f));
        *reinterpret_cast<uint2*>(B2 + (t * 16 + e0) * 132 + (2 * w + c) * 16 + kg * 4) = o.u;
      }
    }
  }
  __syncthreads();

  // ---- Phase 2: L3a — partial sums over K = X2 cols [0,128) ----
  f32x4 acc3[4][2];
#pragma unroll
  for (int t = 0; t < 4; ++t)
#pragma unroll
    for (int c = 0; c < 2; ++c) acc3[t][c] = (f32x4){0.f, 0.f, 0.f, 0.f};
#pragma unroll
  for (int t = 0; t < 4; ++t) {
    const f16* pa = B2 + (t * 16 + e0) * 132 + kg * 8;
    U16x8 a[4];
#pragma unroll
    for (int kt = 0; kt < 4; ++kt) {
      a[kt].p.lo = *(const uint2*)(pa + kt * 32);
      a[kt].p.hi = *(const uint2*)(pa + kt * 32 + 4);
    }
#pragma unroll
    for (int c = 0; c < 2; ++c)
#pragma unroll
      for (int kt = 0; kt < 4; ++kt)
        acc3[t][c] = __builtin_amdgcn_mfma_f32_16x16x32_f16(bfb[c * 4 + kt], a[kt].v, acc3[t][c], 0, 0, 0);
  }
  __syncthreads();

  // ---- Phase 3: L2b -> X2 cols [128,256) into B2 (reuses buffer) ----
#pragma unroll
  for (int c = 0; c < 2; ++c)
#pragma unroll
    for (int kt = 0; kt < 4; ++kt)
      bfa[c * 4 + kt] = wp2[((8 + 2 * w + c) * 4 + kt) * 64 + l];
  {
    float4 bb[2];
#pragma unroll
    for (int c = 0; c < 2; ++c)
      bb[c] = *reinterpret_cast<const float4*>(b2 + (8 + 2 * w + c) * 16 + kg * 4);
#pragma unroll
    for (int t = 0; t < 4; ++t) {
      const f16* pa = B1 + (t * 16 + e0) * 132 + kg * 8;
      U16x8 a[4];
#pragma unroll
      for (int kt = 0; kt < 4; ++kt) {
        a[kt].p.lo = *(const uint2*)(pa + kt * 32);
        a[kt].p.hi = *(const uint2*)(pa + kt * 32 + 4);
      }
#pragma unroll
      for (int c = 0; c < 2; ++c) {
        f32x4 acc = {0.f, 0.f, 0.f, 0.f};
#pragma unroll
        for (int kt = 0; kt < 4; ++kt)
          acc = __builtin_amdgcn_mfma_f32_16x16x32_f16(bfa[c * 4 + kt], a[kt].v, acc, 0, 0, 0);
        U32x2 o;
        o.h2[0] = __builtin_amdgcn_cvt_pkrtz(fmaxf(acc[0] + bb[c].x, 0.f),
                                             fmaxf(acc[1] + bb[c].y, 0.f));
        o.h2[1] = __builtin_amdgcn_cvt_pkrtz(fmaxf(acc[2] + bb[c].z, 0.f),
                                             fmaxf(acc[3] + bb[c].w, 0.f));
        *reinterpret_cast<uint2*>(B2 + (t * 16 + e0) * 132 + (2 * w + c) * 16 + kg * 4) = o.u;
      }
    }
  }
  __syncthreads();

  // ---- Phase 4: L3b — finish K (W3 kt 4..7), bias+ReLU, X3 -> B1 ----
#pragma unroll
  for (int c = 0; c < 2; ++c)
#pragma unroll
    for (int kt = 0; kt < 4; ++kt)
      bfb[c * 4 + kt] = wp3[((2 * w + c) * 8 + 4 + kt) * 64 + l];
#pragma unroll
  for (int t = 0; t < 4; ++t) {
    const f16* pa = B2 + (t * 16 + e0) * 132 + kg * 8;
    U16x8 a[4];
#pragma unroll
    for (int kt = 0; kt < 4; ++kt) {
      a[kt].p.lo = *(const uint2*)(pa + kt * 32);
      a[kt].p.hi = *(const uint2*)(pa + kt * 32 + 4);
    }
#pragma unroll
    for (int c = 0; c < 2; ++c)
#pragma unroll
      for (int kt = 0; kt < 4; ++kt)
        acc3[t][c] = __builtin_amdgcn_mfma_f32_16x16x32_f16(bfb[c * 4 + kt], a[kt].v, acc3[t][c], 0, 0, 0);
  }
  {
    float4 bb[2];
#pragma unroll
    for (int c = 0; c < 2; ++c)
      bb[c] = *reinterpret_cast<const float4*>(b3 + (2 * w + c) * 16 + kg * 4);
#pragma unroll
    for (int t = 0; t < 4; ++t)
#pragma unroll
      for (int c = 0; c < 2; ++c) {
        U32x2 o;
        o.h2[0] = __builtin_amdgcn_cvt_pkrtz(fmaxf(acc3[t][c][0] + bb[c].x, 0.f),
                                             fmaxf(acc3[t][c][1] + bb[c].y, 0.f));
        o.h2[1] = __builtin_amdgcn_cvt_pkrtz(fmaxf(acc3[t][c][2] + bb[c].z, 0.f),
                                             fmaxf(acc3[t][c][3] + bb[c].w, 0.f));
        *reinterpret_cast<uint2*>(B1 + (t * 16 + e0) * 132 + (2 * w + c) * 16 + kg * 4) = o.u;
      }
  }
  __syncthreads();

  // ---- Phase 5: L4 (folded 128->32), scale by s_e, coalesced f32x4 store --
  {
    const int ct = w & 1;
    const int tb = (w >> 1) * 2;
    f16x8 bfr4[4];
#pragma unroll
    for (int kt = 0; kt < 4; ++kt) bfr4[kt] = wp4[(ct * 4 + kt) * 64 + l];
    float4 bb = *reinterpret_cast<const float4*>(b4r + ct * 16 + kg * 4);
#pragma unroll
    for (int ti = 0; ti < 2; ++ti) {
      int t = tb + ti;
      const f16* pa = B1 + (t * 16 + e0) * 132 + kg * 8;
      U16x8 a[4];
#pragma unroll
      for (int kt = 0; kt < 4; ++kt) {
        a[kt].p.lo = *(const uint2*)(pa + kt * 32);
        a[kt].p.hi = *(const uint2*)(pa + kt * 32 + 4);
      }
      f32x4 acc = {0.f, 0.f, 0.f, 0.f};
#pragma unroll
      for (int kt = 0; kt < 4; ++kt)
        acc = __builtin_amdgcn_mfma_f32_16x16x32_f16(bfr4[kt], a[kt].v, acc, 0, 0, 0);
      size_t e = row0 + t * 16 + e0;
      float s = h_w[(e >> 7) * 32 + ((e & 127) >> 2)];
      float4 st;
      st.x = s * (acc[0] + bb.x); st.y = s * (acc[1] + bb.y);
      st.z = s * (acc[2] + bb.z); st.w = s * (acc[3] + bb.w);
      *reinterpret_cast<float4*>(out + e * 32 + ct * 16 + kg * 4) = st;
    }
  }
}

// ---------------------------------------------------------------------------
extern "C" void kernel_launch(void* const* d_in, const int* in_sizes, int n_in,
                              void* d_out, int out_size, void* d_ws, size_t ws_size,
                              hipStream_t stream) {
  // inputs: h_v, h_w, e_vw, W1, b1, W2, b2, W3, b3, W4, b4
  const float* h_w  = (const float*)d_in[1];
  const float* e_vw = (const float*)d_in[2];
  const float* W1   = (const float*)d_in[3];
  const float* b1   = (const float*)d_in[4];
  const float* W2   = (const float*)d_in[5];
  const float* b2   = (const float*)d_in[6];
  const float* W3   = (const float*)d_in[7];
  const float* b3   = (const float*)d_in[8];
  const float* W4   = (const float*)d_in[9];
  const float* b4   = (const float*)d_in[10];
  float* out = (float*)d_out;

  f16*   wsh = (f16*)d_ws;
  float* b4r = (float*)((char*)d_ws + (size_t)WS_HALFS * 2);

  const int E = in_sizes[2] / 16;  // 131072

  hipLaunchKernelGGL(prep_kernel, dim3(288), dim3(256), 0, stream,
                     W1, b1, W2, W3, W4, b4, wsh, b4r);
  hipLaunchKernelGGL(mlp_mfma_kernel, dim3(E / 64), dim3(256), 0, stream,
                     e_vw, h_w, b2, b3, wsh, b4r, out);
}

// Round 9
// 33.221 us; speedup vs baseline: 1.1994x; 1.1994x over previous
//
#include <hip/hip_runtime.h>

// E = 8*128*128 edges; MLP 16->128->256->128->(32x32 folded to 32)
// fp16 MFMA 16x16x32, swapped operands (W as A-frag -> lane owns one edge).
// Round 9: revert to round-6 skeleton (proven 32.6us: 4 waves col-sliced,
// full-width X2, no cross-phase accumulators) + the one safe round-7 piece:
// L1 A-frags built directly from global (staging phase & barrier deleted).
// Phases: L1 | L2 | L3 | L4, 3 barriers (structural minimum).

typedef _Float16 f16;
typedef _Float16 f16x8 __attribute__((ext_vector_type(8)));
typedef __fp16 fp16x2 __attribute__((ext_vector_type(2)));   // cvt_pkrtz return type
typedef float f32x4 __attribute__((ext_vector_type(4)));

#define OFF_W1S 0        // [8 ct][64 lane][8]   (K=16 padded: row16 = b1)
#define OFF_W2S 4096     // [16 ct][4 kt][64][8]
#define OFF_W3S 36864    // [8 ct][8 kt][64][8]
#define OFF_W4S 69632    // [2 ct][4 kt][64][8]  (W4 folded over inner i)
#define WS_HALFS 73728

union U16x8 { struct { uint2 lo, hi; } p; f16x8 v; };
union U32x2 { fp16x2 h2[2]; uint2 u; };

// ---------------------------------------------------------------------------
// Pre-kernel: fold W4 over i, convert weights to fp16 in fragment order:
// element j of lane l for col-tile ct, k-tile kt is
// W[kt*32 + (l>>4)*8 + j][ct*16 + (l&15)].  W1 row 16 carries b1.
// ---------------------------------------------------------------------------
__global__ void prep_kernel(const float* __restrict__ W1, const float* __restrict__ b1,
                            const float* __restrict__ W2, const float* __restrict__ W3,
                            const float* __restrict__ W4, const float* __restrict__ b4,
                            f16* __restrict__ wsh, float* __restrict__ b4r) {
  int t = blockIdx.x * 256 + threadIdx.x;
  if (t < 4096) {                       // W1s (K 16 + bias row + zeros)
    int j = t & 7, l = (t >> 3) & 63, ct = t >> 9;
    int k = ((l >> 4) & 3) * 8 + j, c = ct * 16 + (l & 15);
    wsh[OFF_W1S + t] = (k < 16) ? (f16)W1[k * 128 + c]
                                : (k == 16 ? (f16)b1[c] : (f16)0.f);
  } else if (t < 36864) {               // W2s
    int s = t - 4096;
    int j = s & 7, l = (s >> 3) & 63, kt = (s >> 9) & 3, ct = s >> 11;
    int k = kt * 32 + ((l >> 4) & 3) * 8 + j, c = ct * 16 + (l & 15);
    wsh[t] = (f16)W2[k * 256 + c];
  } else if (t < 69632) {               // W3s
    int s = t - 36864;
    int j = s & 7, l = (s >> 3) & 63, kt = (s >> 9) & 7, ct = s >> 12;
    int k = kt * 32 + ((l >> 4) & 3) * 8 + j, c = ct * 16 + (l & 15);
    wsh[t] = (f16)W3[k * 128 + c];
  } else if (t < 73728) {               // W4rs (folded over i)
    int s = t - 69632;
    int j = s & 7, l = (s >> 3) & 63, kt = (s >> 9) & 3, ct = s >> 11;
    int k = kt * 32 + ((l >> 4) & 3) * 8 + j, o = ct * 16 + (l & 15);
    float a = 0.f;
#pragma unroll
    for (int i = 0; i < 32; ++i) a += W4[k * 1024 + o * 32 + i];
    wsh[t] = (f16)a;
  }
  if (t < 32) {
    float a = 0.f;
#pragma unroll
    for (int i = 0; i < 32; ++i) a += b4[t * 32 + i];
    b4r[t] = a;
  }
}

// ---------------------------------------------------------------------------
// Fused MLP, 64 edges/block, 4 waves, column-sliced:
//   L1: wave owns cols [w*32, w*32+32)   (A-frag direct from global)
//   L2: wave owns cols [w*64, w*64+64)
//   L3: wave owns cols [w*32, w*32+32)
//   L4: wave (w&1) owns col-tile, (w>>1) owns row half
// LDS: P = X1 then X3 (64x132, 16.5 KB); Q = X2 (64x260, 32.5 KB). 49 KB.
// ---------------------------------------------------------------------------
__global__ __launch_bounds__(256, 3) void mlp_mfma_kernel(
    const float* __restrict__ e_vw, const float* __restrict__ h_w,
    const float* __restrict__ b2, const float* __restrict__ b3,
    const f16* __restrict__ wsh, const float* __restrict__ b4r,
    float* __restrict__ out) {
  __shared__ f16 P[64 * 132];   // X1, later X3
  __shared__ f16 Q[64 * 260];   // X2

  const int l  = threadIdx.x & 63;
  const int w  = threadIdx.x >> 6;
  const int e0 = l & 15;          // edge-within-tile
  const int kg = l >> 4;          // k-group; packed out-cols kg*4..kg*4+3
  const size_t row0 = (size_t)blockIdx.x * 64;

  const f16x8* wp1 = (const f16x8*)(wsh + OFF_W1S);
  const f16x8* wp2 = (const f16x8*)(wsh + OFF_W2S);
  const f16x8* wp3 = (const f16x8*)(wsh + OFF_W3S);
  const f16x8* wp4 = (const f16x8*)(wsh + OFF_W4S);

  // ---- Phase 0: L1 (A-frag direct from global; b1 folded in K-slot 16) ----
  {
    f16x8 bfr1[2];
#pragma unroll
    for (int c = 0; c < 2; ++c) bfr1[c] = wp1[(2 * w + c) * 64 + l];
#pragma unroll
    for (int t = 0; t < 4; ++t) {
      U16x8 a;
      if (kg < 2) {
        const float* pe = e_vw + (row0 + t * 16 + e0) * 16 + kg * 8;
        float4 v0 = *reinterpret_cast<const float4*>(pe);
        float4 v1 = *reinterpret_cast<const float4*>(pe + 4);
        U32x2 c0, c1;
        c0.h2[0] = __builtin_amdgcn_cvt_pkrtz(v0.x, v0.y);
        c0.h2[1] = __builtin_amdgcn_cvt_pkrtz(v0.z, v0.w);
        c1.h2[0] = __builtin_amdgcn_cvt_pkrtz(v1.x, v1.y);
        c1.h2[1] = __builtin_amdgcn_cvt_pkrtz(v1.z, v1.w);
        a.p.lo = c0.u; a.p.hi = c1.u;
      } else {
        a.p.lo.x = (kg == 2) ? 0x00003C00u : 0u;   // k=16 -> 1.0 (bias slot)
        a.p.lo.y = 0u; a.p.hi.x = 0u; a.p.hi.y = 0u;
      }
#pragma unroll
      for (int c = 0; c < 2; ++c) {
        f32x4 acc = {0.f, 0.f, 0.f, 0.f};
        acc = __builtin_amdgcn_mfma_f32_16x16x32_f16(bfr1[c], a.v, acc, 0, 0, 0);
        U32x2 o;
        o.h2[0] = __builtin_amdgcn_cvt_pkrtz(fmaxf(acc[0], 0.f), fmaxf(acc[1], 0.f));
        o.h2[1] = __builtin_amdgcn_cvt_pkrtz(fmaxf(acc[2], 0.f), fmaxf(acc[3], 0.f));
        *reinterpret_cast<uint2*>(P + (t * 16 + e0) * 132 + (2 * w + c) * 16 + kg * 4) = o.u;
      }
    }
  }
  // prefetch L2 frags (latency overlaps the barrier)
  f16x8 bfr2[16];
#pragma unroll
  for (int c = 0; c < 4; ++c)
#pragma unroll
    for (int kt = 0; kt < 4; ++kt)
      bfr2[c * 4 + kt] = wp2[((4 * w + c) * 4 + kt) * 64 + l];
  __syncthreads();

  // ---- Phase 1: L2: 128 -> 256 (wave owns cols [w*64, w*64+64)) ----
  {
    float4 bb[4];
#pragma unroll
    for (int c = 0; c < 4; ++c)
      bb[c] = *reinterpret_cast<const float4*>(b2 + (4 * w + c) * 16 + kg * 4);
#pragma unroll
    for (int t = 0; t < 4; ++t) {
      const f16* pa = P + (t * 16 + e0) * 132 + kg * 8;
      U16x8 a[4];
#pragma unroll
      for (int kt = 0; kt < 4; ++kt) {
        a[kt].p.lo = *(const uint2*)(pa + kt * 32);
        a[kt].p.hi = *(const uint2*)(pa + kt * 32 + 4);
      }
#pragma unroll
      for (int c = 0; c < 4; ++c) {
        f32x4 acc = {0.f, 0.f, 0.f, 0.f};
#pragma unroll
        for (int kt = 0; kt < 4; ++kt)
          acc = __builtin_amdgcn_mfma_f32_16x16x32_f16(bfr2[c * 4 + kt], a[kt].v, acc, 0, 0, 0);
        U32x2 o;
        o.h2[0] = __builtin_amdgcn_cvt_pkrtz(fmaxf(acc[0] + bb[c].x, 0.f),
                                             fmaxf(acc[1] + bb[c].y, 0.f));
        o.h2[1] = __builtin_amdgcn_cvt_pkrtz(fmaxf(acc[2] + bb[c].z, 0.f),
                                             fmaxf(acc[3] + bb[c].w, 0.f));
        *reinterpret_cast<uint2*>(Q + (t * 16 + e0) * 260 + (4 * w + c) * 16 + kg * 4) = o.u;
      }
    }
  }
  // prefetch L3 frags
  f16x8 bfr3[16];
#pragma unroll
  for (int c = 0; c < 2; ++c)
#pragma unroll
    for (int kt = 0; kt < 8; ++kt)
      bfr3[c * 8 + kt] = wp3[((2 * w + c) * 8 + kt) * 64 + l];
  __syncthreads();

  // ---- Phase 2: L3: 256 -> 128 (wave owns cols [w*32, w*32+32)) ----
  {
    float4 bb[2];
#pragma unroll
    for (int c = 0; c < 2; ++c)
      bb[c] = *reinterpret_cast<const float4*>(b3 + (2 * w + c) * 16 + kg * 4);
#pragma unroll
    for (int t = 0; t < 4; ++t) {
      const f16* pa = Q + (t * 16 + e0) * 260 + kg * 8;
      U16x8 a[8];
#pragma unroll
      for (int kt = 0; kt < 8; ++kt) {
        a[kt].p.lo = *(const uint2*)(pa + kt * 32);
        a[kt].p.hi = *(const uint2*)(pa + kt * 32 + 4);
      }
#pragma unroll
      for (int c = 0; c < 2; ++c) {
        f32x4 acc = {0.f, 0.f, 0.f, 0.f};
#pragma unroll
        for (int kt = 0; kt < 8; ++kt)
          acc = __builtin_amdgcn_mfma_f32_16x16x32_f16(bfr3[c * 8 + kt], a[kt].v, acc, 0, 0, 0);
        U32x2 o;
        o.h2[0] = __builtin_amdgcn_cvt_pkrtz(fmaxf(acc[0] + bb[c].x, 0.f),
                                             fmaxf(acc[1] + bb[c].y, 0.f));
        o.h2[1] = __builtin_amdgcn_cvt_pkrtz(fmaxf(acc[2] + bb[c].z, 0.f),
                                             fmaxf(acc[3] + bb[c].w, 0.f));
        *reinterpret_cast<uint2*>(P + (t * 16 + e0) * 132 + (2 * w + c) * 16 + kg * 4) = o.u;
      }
    }
  }
  // prefetch L4 frags
  const int ct = w & 1;
  const int tb = (w >> 1) * 2;
  f16x8 bfr4[4];
#pragma unroll
  for (int kt = 0; kt < 4; ++kt) bfr4[kt] = wp4[(ct * 4 + kt) * 64 + l];
  __syncthreads();

  // ---- Phase 3: L4 (folded 128->32), scale by s_e, coalesced f32x4 store --
  {
    float4 bb = *reinterpret_cast<const float4*>(b4r + ct * 16 + kg * 4);
#pragma unroll
    for (int ti = 0; ti < 2; ++ti) {
      int t = tb + ti;
      const f16* pa = P + (t * 16 + e0) * 132 + kg * 8;
      U16x8 a[4];
#pragma unroll
      for (int kt = 0; kt < 4; ++kt) {
        a[kt].p.lo = *(const uint2*)(pa + kt * 32);
        a[kt].p.hi = *(const uint2*)(pa + kt * 32 + 4);
      }
      f32x4 acc = {0.f, 0.f, 0.f, 0.f};
#pragma unroll
      for (int kt = 0; kt < 4; ++kt)
        acc = __builtin_amdgcn_mfma_f32_16x16x32_f16(bfr4[kt], a[kt].v, acc, 0, 0, 0);
      size_t e = row0 + t * 16 + e0;
      float s = h_w[(e >> 7) * 32 + ((e & 127) >> 2)];
      float4 st;
      st.x = s * (acc[0] + bb.x); st.y = s * (acc[1] + bb.y);
      st.z = s * (acc[2] + bb.z); st.w = s * (acc[3] + bb.w);
      *reinterpret_cast<float4*>(out + e * 32 + ct * 16 + kg * 4) = st;
    }
  }
}

// ---------------------------------------------------------------------------
extern "C" void kernel_launch(void* const* d_in, const int* in_sizes, int n_in,
                              void* d_out, int out_size, void* d_ws, size_t ws_size,
                              hipStream_t stream) {
  // inputs: h_v, h_w, e_vw, W1, b1, W2, b2, W3, b3, W4, b4
  const float* h_w  = (const float*)d_in[1];
  const float* e_vw = (const float*)d_in[2];
  const float* W1   = (const float*)d_in[3];
  const float* b1   = (const float*)d_in[4];
  const float* W2   = (const float*)d_in[5];
  const float* b2   = (const float*)d_in[6];
  const float* W3   = (const float*)d_in[7];
  const float* b3   = (const float*)d_in[8];
  const float* W4   = (const float*)d_in[9];
  const float* b4   = (const float*)d_in[10];
  float* out = (float*)d_out;

  f16*   wsh = (f16*)d_ws;
  float* b4r = (float*)((char*)d_ws + (size_t)WS_HALFS * 2);

  const int E = in_sizes[2] / 16;  // 131072

  hipLaunchKernelGGL(prep_kernel, dim3(288), dim3(256), 0, stream,
                     W1, b1, W2, W3, W4, b4, wsh, b4r);
  hipLaunchKernelGGL(mlp_mfma_kernel, dim3(E / 64), dim3(256), 0, stream,
                     e_vw, h_w, b2, b3, wsh, b4r, out);
}

// Round 10
// 30.035 us; speedup vs baseline: 1.3267x; 1.1061x over previous
//
#include <hip/hip_runtime.h>

// E = 8*128*128 edges; MLP 16->128->256->128->(32x32 folded to 32)
// Round 10: fully register-resident activation chain, barrier-free waves.
//   - swapped-operand MFMA 16x16x32: D lane layout (edge=l&15, feat u*4+r)
//   - weight k-labeling F(u,j) = kt*32 + (j>>2)*16 + u*4 + (j&3) makes the
//     next layer's B-frag = concat of two packed D dwords (no shuffle!)
//   - W2s/W3s (128 KB) preloaded to LDS once; W1s/W4s frags from L2
//   - 512 blocks x 8 waves x 2 tiles (32 edges)/wave; frag reads shared
//     across the 2 tiles; one barrier total (after preload)

typedef _Float16 f16;
typedef _Float16 f16x8 __attribute__((ext_vector_type(8)));
typedef __fp16 fp16x2 __attribute__((ext_vector_type(2)));
typedef float f32x4 __attribute__((ext_vector_type(4)));

#define OFF_W1S 0        // [8 ct][64 lane][8]  (K=16 padded: k16 = b1) natural k
#define OFF_W2S 4096     // [16 ct][4 kt][64][8]  F-permuted k
#define OFF_W3S 36864    // [8 ct][8 kt][64][8]   F-permuted k
#define OFF_W4S 69632    // [2 ct][4 kt][64][8]   F-permuted k, folded over i
#define WS_HALFS 73728

union U16x8 { struct { uint2 lo, hi; } p; f16x8 v; };
union U32x2 { fp16x2 h2[2]; uint2 u; };

// ---------------------------------------------------------------------------
// Pre-kernel. A-frag element j of lane l (u=(l>>4)&3) for (ct, kt) holds
// W[k_feat][ct*16 + (l&15)] with k_feat = kt*32 + (j>>2)*16 + u*4 + (j&3)
// (the F-labeling that matches register-resident activations). W1 keeps the
// natural labeling k = u*8 + j (input comes from global in natural order),
// with row 16 = b1 (bias folded into the K-pad).
// ---------------------------------------------------------------------------
__global__ void prep_kernel(const float* __restrict__ W1, const float* __restrict__ b1,
                            const float* __restrict__ W2, const float* __restrict__ W3,
                            const float* __restrict__ W4, const float* __restrict__ b4,
                            f16* __restrict__ wsh, float* __restrict__ b4r) {
  int t = blockIdx.x * 256 + threadIdx.x;
  if (t < 4096) {                       // W1s: natural k (16 + bias row + zeros)
    int j = t & 7, lq = (t >> 3) & 63, ct = t >> 9;
    int k = ((lq >> 4) & 3) * 8 + j, c = ct * 16 + (lq & 15);
    wsh[OFF_W1S + t] = (k < 16) ? (f16)W1[k * 128 + c]
                                : (k == 16 ? (f16)b1[c] : (f16)0.f);
  } else if (t < 36864) {               // W2s: F-permuted
    int s = t - 4096;
    int j = s & 7, lq = (s >> 3) & 63, kt = (s >> 9) & 3, ct = s >> 11;
    int u = (lq >> 4) & 3;
    int k = kt * 32 + (j >> 2) * 16 + u * 4 + (j & 3), c = ct * 16 + (lq & 15);
    wsh[t] = (f16)W2[k * 256 + c];
  } else if (t < 69632) {               // W3s: F-permuted
    int s = t - 36864;
    int j = s & 7, lq = (s >> 3) & 63, kt = (s >> 9) & 7, ct = s >> 12;
    int u = (lq >> 4) & 3;
    int k = kt * 32 + (j >> 2) * 16 + u * 4 + (j & 3), c = ct * 16 + (lq & 15);
    wsh[t] = (f16)W3[k * 128 + c];
  } else if (t < 73728) {               // W4s: F-permuted, folded over inner i
    int s = t - 69632;
    int j = s & 7, lq = (s >> 3) & 63, kt = (s >> 9) & 3, ct = s >> 11;
    int u = (lq >> 4) & 3;
    int k = kt * 32 + (j >> 2) * 16 + u * 4 + (j & 3), o = ct * 16 + (lq & 15);
    float a = 0.f;
#pragma unroll
    for (int i = 0; i < 32; ++i) a += W4[k * 1024 + o * 32 + i];
    wsh[t] = (f16)a;
  }
  if (t < 32) {
    float a = 0.f;
#pragma unroll
    for (int i = 0; i < 32; ++i) a += b4[t * 32 + i];
    b4r[t] = a;
  }
}

__device__ __forceinline__ uint2 relu_pack(f32x4 a) {
  U32x2 o;
  o.h2[0] = __builtin_amdgcn_cvt_pkrtz(fmaxf(a[0], 0.f), fmaxf(a[1], 0.f));
  o.h2[1] = __builtin_amdgcn_cvt_pkrtz(fmaxf(a[2], 0.f), fmaxf(a[3], 0.f));
  return o.u;
}
__device__ __forceinline__ uint2 bias_relu_pack(f32x4 a, float4 b) {
  U32x2 o;
  o.h2[0] = __builtin_amdgcn_cvt_pkrtz(fmaxf(a[0] + b.x, 0.f), fmaxf(a[1] + b.y, 0.f));
  o.h2[1] = __builtin_amdgcn_cvt_pkrtz(fmaxf(a[2] + b.z, 0.f), fmaxf(a[3] + b.w, 0.f));
  return o.u;
}

// ---------------------------------------------------------------------------
// Fused MLP: 512 threads (8 waves), each wave owns 32 edges (2 16-edge tiles,
// interleaved so each weight frag is read once and used twice). Activations
// live in VGPRs end-to-end. One barrier (weight preload); waves independent.
// ---------------------------------------------------------------------------
__global__ __launch_bounds__(512, 2) void mlp_mfma_kernel(
    const float* __restrict__ e_vw, const float* __restrict__ h_w,
    const float* __restrict__ b2, const float* __restrict__ b3,
    const f16* __restrict__ wsh, const float* __restrict__ b4r,
    float* __restrict__ out) {
  __shared__ f16 WT[65536];   // 128 KB: [0,32768) W2s', [32768,65536) W3s'

  const int tid = threadIdx.x;
  const int l = tid & 63, w = tid >> 6;
  const int e0 = l & 15, u = l >> 4;
  const size_t base = (size_t)blockIdx.x * 256 + (size_t)w * 32;

  const f16x8* wp1 = (const f16x8*)(wsh + OFF_W1S);
  const f16x8* wp4 = (const f16x8*)(wsh + OFF_W4S);

  // ---- stage inputs + L1 frags (global; overlaps preload) ----
  U16x8 xin[2];
#pragma unroll
  for (int ti = 0; ti < 2; ++ti) {
    if (u < 2) {
      const float* pe = e_vw + (base + ti * 16 + e0) * 16 + u * 8;
      float4 v0 = *reinterpret_cast<const float4*>(pe);
      float4 v1 = *reinterpret_cast<const float4*>(pe + 4);
      U32x2 c0, c1;
      c0.h2[0] = __builtin_amdgcn_cvt_pkrtz(v0.x, v0.y);
      c0.h2[1] = __builtin_amdgcn_cvt_pkrtz(v0.z, v0.w);
      c1.h2[0] = __builtin_amdgcn_cvt_pkrtz(v1.x, v1.y);
      c1.h2[1] = __builtin_amdgcn_cvt_pkrtz(v1.z, v1.w);
      xin[ti].p.lo = c0.u; xin[ti].p.hi = c1.u;
    } else {
      xin[ti].p.lo.x = (u == 2) ? 0x00003C00u : 0u;  // k=16 -> 1.0 (bias slot)
      xin[ti].p.lo.y = 0u; xin[ti].p.hi.x = 0u; xin[ti].p.hi.y = 0u;
    }
  }
  f16x8 w1f[8];
#pragma unroll
  for (int ct = 0; ct < 8; ++ct) w1f[ct] = wp1[ct * 64 + l];

  // ---- preload W2s'/W3s' into LDS (131072 B, 16 float4 per thread) ----
  {
    const float4* src = (const float4*)(wsh + OFF_W2S);
    float4* dst = (float4*)WT;
#pragma unroll
    for (int i = 0; i < 16; ++i) dst[tid + i * 512] = src[tid + i * 512];
  }
  __syncthreads();

  // ---- L1: 16 -> 128 (bias folded in K-pad) ----
  U16x8 x1[2][4];
  const f32x4 z4 = {0.f, 0.f, 0.f, 0.f};
#pragma unroll
  for (int ct = 0; ct < 8; ++ct) {
    f32x4 a0 = __builtin_amdgcn_mfma_f32_16x16x32_f16(w1f[ct], xin[0].v, z4, 0, 0, 0);
    f32x4 a1 = __builtin_amdgcn_mfma_f32_16x16x32_f16(w1f[ct], xin[1].v, z4, 0, 0, 0);
    uint2 d0 = relu_pack(a0), d1 = relu_pack(a1);
    if (ct & 1) { x1[0][ct >> 1].p.hi = d0; x1[1][ct >> 1].p.hi = d1; }
    else        { x1[0][ct >> 1].p.lo = d0; x1[1][ct >> 1].p.lo = d1; }
  }

  // ---- L2: 128 -> 256 (weights from LDS; B-frag = x1[kt] directly) ----
  U16x8 x2[2][8];
#pragma unroll
  for (int ct = 0; ct < 16; ++ct) {
    f32x4 a0 = z4, a1 = z4;
#pragma unroll
    for (int kt = 0; kt < 4; ++kt) {
      f16x8 wf = *(const f16x8*)(WT + ((ct * 4 + kt) * 64 + l) * 8);
      a0 = __builtin_amdgcn_mfma_f32_16x16x32_f16(wf, x1[0][kt].v, a0, 0, 0, 0);
      a1 = __builtin_amdgcn_mfma_f32_16x16x32_f16(wf, x1[1][kt].v, a1, 0, 0, 0);
    }
    float4 bb = *reinterpret_cast<const float4*>(b2 + ct * 16 + u * 4);
    uint2 d0 = bias_relu_pack(a0, bb), d1 = bias_relu_pack(a1, bb);
    if (ct & 1) { x2[0][ct >> 1].p.hi = d0; x2[1][ct >> 1].p.hi = d1; }
    else        { x2[0][ct >> 1].p.lo = d0; x2[1][ct >> 1].p.lo = d1; }
  }

  // ---- L3: 256 -> 128 ----
  U16x8 x3[2][4];
#pragma unroll
  for (int ct = 0; ct < 8; ++ct) {
    f32x4 a0 = z4, a1 = z4;
#pragma unroll
    for (int kt = 0; kt < 8; ++kt) {
      f16x8 wf = *(const f16x8*)(WT + 32768 + ((ct * 8 + kt) * 64 + l) * 8);
      a0 = __builtin_amdgcn_mfma_f32_16x16x32_f16(wf, x2[0][kt].v, a0, 0, 0, 0);
      a1 = __builtin_amdgcn_mfma_f32_16x16x32_f16(wf, x2[1][kt].v, a1, 0, 0, 0);
    }
    float4 bb = *reinterpret_cast<const float4*>(b3 + ct * 16 + u * 4);
    uint2 d0 = bias_relu_pack(a0, bb), d1 = bias_relu_pack(a1, bb);
    if (ct & 1) { x3[0][ct >> 1].p.hi = d0; x3[1][ct >> 1].p.hi = d1; }
    else        { x3[0][ct >> 1].p.lo = d0; x3[1][ct >> 1].p.lo = d1; }
  }

  // ---- L4: 128 -> 32 (folded), scale by s_e, coalesced float4 store ----
#pragma unroll
  for (int ti = 0; ti < 2; ++ti) {
    size_t e = base + ti * 16 + e0;
    float s = h_w[(e >> 7) * 32 + ((e & 127) >> 2)];
#pragma unroll
    for (int ct = 0; ct < 2; ++ct) {
      f32x4 acc = z4;
#pragma unroll
      for (int kt = 0; kt < 4; ++kt)
        acc = __builtin_amdgcn_mfma_f32_16x16x32_f16(wp4[(ct * 4 + kt) * 64 + l],
                                                     x3[ti][kt].v, acc, 0, 0, 0);
      float4 bb = *reinterpret_cast<const float4*>(b4r + ct * 16 + u * 4);
      float4 st;
      st.x = s * (acc[0] + bb.x); st.y = s * (acc[1] + bb.y);
      st.z = s * (acc[2] + bb.z); st.w = s * (acc[3] + bb.w);
      *reinterpret_cast<float4*>(out + e * 32 + ct * 16 + u * 4) = st;
    }
  }
}

// ---------------------------------------------------------------------------
extern "C" void kernel_launch(void* const* d_in, const int* in_sizes, int n_in,
                              void* d_out, int out_size, void* d_ws, size_t ws_size,
                              hipStream_t stream) {
  // inputs: h_v, h_w, e_vw, W1, b1, W2, b2, W3, b3, W4, b4
  const float* h_w  = (const float*)d_in[1];
  const float* e_vw = (const float*)d_in[2];
  const float* W1   = (const float*)d_in[3];
  const float* b1   = (const float*)d_in[4];
  const float* W2   = (const float*)d_in[5];
  const float* b2   = (const float*)d_in[6];
  const float* W3   = (const float*)d_in[7];
  const float* b3   = (const float*)d_in[8];
  const float* W4   = (const float*)d_in[9];
  const float* b4   = (const float*)d_in[10];
  float* out = (float*)d_out;

  f16*   wsh = (f16*)d_ws;
  float* b4r = (float*)((char*)d_ws + (size_t)WS_HALFS * 2);

  const int E = in_sizes[2] / 16;       // 131072
  const int blocks = E / 256;           // 512 (8 waves x 32 edges each)

  hipLaunchKernelGGL(prep_kernel, dim3(288), dim3(256), 0, stream,
                     W1, b1, W2, W3, W4, b4, wsh, b4r);
  hipLaunchKernelGGL(mlp_mfma_kernel, dim3(blocks), dim3(512), 0, stream,
                     e_vw, h_w, b2, b3, wsh, b4r, out);
}